// Round 12
// baseline (1705.866 us; speedup 1.0000x reference)
//
#include <hip/hip_runtime.h>

#define B_   8
#define N1_  8192
#define N2_  1024
#define K_   32
#define F1_  64
#define CIN_ 67
#define M1_  64
#define M2_  64
#define M3_  128
#define HSTR 40          // LDS activation row stride (floats)
#define FLTMAX 3.402823466e+38f

#define TPB  512         // block size (1024 fails to launch on this harness — R8/R9)
#define FNW  (TPB/64)    // waves per block = 8
#define PPT  (N1_/TPB)   // fps points per thread = 16
#define PPC  16          // consumer points per thread (8192/512)

// order-preserving float->uint key (monotone incl. negatives; equal keys <=> equal bits)
__device__ __forceinline__ unsigned f2key(float f) {
  unsigned u = __float_as_uint(f);
  return u ^ ((unsigned)((int)u >> 31) | 0x80000000u);
}

// 6-step DPP wave64 reduce (row_shr 1/2/4/8 + row_bcast 15/31), broadcast via readlane(63).
__device__ __forceinline__ unsigned dpp_umax_bcast(unsigned v) {
  unsigned o;
  o = (unsigned)__builtin_amdgcn_update_dpp(0, (int)v, 0x111, 0xf, 0xf, false); v = v > o ? v : o;
  o = (unsigned)__builtin_amdgcn_update_dpp(0, (int)v, 0x112, 0xf, 0xf, false); v = v > o ? v : o;
  o = (unsigned)__builtin_amdgcn_update_dpp(0, (int)v, 0x114, 0xf, 0xf, false); v = v > o ? v : o;
  o = (unsigned)__builtin_amdgcn_update_dpp(0, (int)v, 0x118, 0xf, 0xf, false); v = v > o ? v : o;
  o = (unsigned)__builtin_amdgcn_update_dpp(0, (int)v, 0x142, 0xf, 0xf, false); v = v > o ? v : o;
  o = (unsigned)__builtin_amdgcn_update_dpp(0, (int)v, 0x143, 0xf, 0xf, false); v = v > o ? v : o;
  return (unsigned)__builtin_amdgcn_readlane((int)v, 63);
}
__device__ __forceinline__ unsigned dpp_umin_bcast(unsigned v) {
  unsigned o;
  o = (unsigned)__builtin_amdgcn_update_dpp(-1, (int)v, 0x111, 0xf, 0xf, false); v = v < o ? v : o;
  o = (unsigned)__builtin_amdgcn_update_dpp(-1, (int)v, 0x112, 0xf, 0xf, false); v = v < o ? v : o;
  o = (unsigned)__builtin_amdgcn_update_dpp(-1, (int)v, 0x114, 0xf, 0xf, false); v = v < o ? v : o;
  o = (unsigned)__builtin_amdgcn_update_dpp(-1, (int)v, 0x118, 0xf, 0xf, false); v = v < o ? v : o;
  o = (unsigned)__builtin_amdgcn_update_dpp(-1, (int)v, 0x142, 0xf, 0xf, false); v = v < o ? v : o;
  o = (unsigned)__builtin_amdgcn_update_dpp(-1, (int)v, 0x143, 0xf, 0xf, false); v = v < o ? v : o;
  return (unsigned)__builtin_amdgcn_readlane((int)v, 63);
}

// handshake encode: coords in [0,1) -> bits in [0xC0000000, 0xFF7FFFFF]; never 0x0 (memset) or 0xAAAAAAAA (poison)
#define HS_ENC(f) (__float_as_uint(f) ^ 0xC0000000u)
#define HS_DEC(u) __uint_as_float((u) ^ 0xC0000000u)

__global__ __launch_bounds__(TPB, 1) void fused_kernel(
    const float* __restrict__ xyz, const float* __restrict__ feat,
    const float* __restrict__ w0g, const float* __restrict__ b0g,
    const float* __restrict__ w1g, const float* __restrict__ b1g,
    const float* __restrict__ w2g, const float* __restrict__ b2g,
    float* __restrict__ out_xyz, float* __restrict__ out_feat)
{
  __shared__ float4 wslot[2][FNW];                  // fps winner slots
  __shared__ __align__(16) float buf0[CIN_*HSTR];   // consumer activations
  __shared__ __align__(16) float buf1[M1_*HSTR];
  __shared__ float sval[2][FNW];
  __shared__ int   sidx[2][FNW];
  __shared__ float qsh[3];

  const int t = threadIdx.x;
  const int lane = t & 63;
  const int wv_ = t >> 6;

  if (blockIdx.x < B_) {
    // ================= FPS producer: one block per batch (R10-proven core) =================
    __builtin_amdgcn_s_setprio(3);
    const int b = blockIdx.x;
    const float* gxyz = xyz + (size_t)b * (N1_ * 3);
    float* oxyz = out_xyz + (size_t)b * (N2_ * 3);

    float x[PPT], y[PPT], z[PPT], md[PPT];
    {
      const float4* gs = (const float4*)gxyz;
#pragma unroll
      for (int w = 0; w < 12; ++w) {
        const float4 v = gs[t * 12 + w];
#pragma unroll
        for (int c = 0; c < 4; ++c) {
          const int p = w * 4 + c;               // flat float index 0..47
          const float val = (c == 0) ? v.x : (c == 1) ? v.y : (c == 2) ? v.z : v.w;
          const int j = p / 3, cc = p % 3;
          if (cc == 0) x[j] = val; else if (cc == 1) y[j] = val; else z[j] = val;
        }
      }
    }
#pragma unroll
    for (int j = 0; j < PPT; ++j) md[j] = FLTMAX;  // matches jnp.finfo(float32).max init

    if (lane == 0) { float4 s; s.x = -1.0f; s.y = 0.f; s.z = 0.f; s.w = 0.f; wslot[1][wv_] = s; }
    if (t == 0)   { float4 s; s.x = 1.0f; s.y = x[0]; s.z = y[0]; s.w = z[0]; wslot[1][0] = s; }
    __syncthreads();

    for (int i = 1; i < N2_; ++i) {
      const int p = i & 1;
      // winner of iteration i-1: scan slots (strict > keeps lowest wave = lowest idx)
      float4 wb = wslot[p][0];
#pragma unroll
      for (int u = 1; u < FNW; ++u) { const float4 s = wslot[p][u]; if (s.x > wb.x) wb = s; }
      const float px = wb.y, py = wb.z, pz = wb.w;
      if (t == 0) {
        const int g = (b << 10) + (i - 1);
        const int o = (i - 1) * 3;
        oxyz[o] = px; oxyz[o+1] = py; oxyz[o+2] = pz;
        unsigned* hs = (unsigned*)(out_feat + (size_t)g * M3_);
        atomicExch(&hs[0], HS_ENC(px));
        atomicExch(&hs[1], HS_ENC(py));
        atomicExch(&hs[2], HS_ENC(pz));
      }

      // fused distance update + first-max argmax with inline coord tracking
      float bestv, bx, by, bz;
#pragma unroll
      for (int j = 0; j < PPT; ++j) {
        const float dx = __fsub_rn(x[j], px);
        const float dy = __fsub_rn(y[j], py);
        const float dz = __fsub_rn(z[j], pz);
        const float d  = __fadd_rn(__fadd_rn(__fmul_rn(dx,dx), __fmul_rn(dy,dy)), __fmul_rn(dz,dz));
        md[j] = fminf(md[j], d);
        if (j == 0) { bestv = md[0]; bx = x[0]; by = y[0]; bz = z[0]; }
        else {
          const bool c = md[j] > bestv;
          bestv = c ? md[j] : bestv;
          bx = c ? x[j] : bx; by = c ? y[j] : by; bz = c ? z[j] : bz;
        }
      }
      // DPP wave max + ballot winner (lowest lane = lowest point index)
      const unsigned key = f2key(bestv);
      const unsigned kmax = dpp_umax_bcast(key);
      const int fl = __ffsll(__ballot(key == kmax)) - 1;
      if (lane == fl) {
        float4 s; s.x = bestv; s.y = bx; s.z = by; s.w = bz;
        wslot[1 - p][wv_] = s;
      }
      __syncthreads();
    }
    if (t == 0) {   // winner of iteration N2_-1 sits in parity-0 slots
      float4 wb = wslot[0][0];
#pragma unroll
      for (int u = 1; u < FNW; ++u) { const float4 s = wslot[0][u]; if (s.x > wb.x) wb = s; }
      const int g = (b << 10) + (N2_ - 1);
      const int o = (N2_ - 1) * 3;
      oxyz[o] = wb.y; oxyz[o+1] = wb.z; oxyz[o+2] = wb.w;
      unsigned* hs = (unsigned*)(out_feat + (size_t)g * M3_);
      atomicExch(&hs[0], HS_ENC(wb.y));
      atomicExch(&hs[1], HS_ENC(wb.z));
      atomicExch(&hs[2], HS_ENC(wb.w));
    }
    return;
  }

  // ================= KNN + MLP + maxpool consumer: one 512-thread block per query =================
  const int bq = blockIdx.x - B_;
  const int b  = bq >> 10;
  const float* gxyz = xyz + (size_t)b * (N1_ * 3);

  if (t == 0) {
    unsigned* hs = (unsigned*)(out_feat + (size_t)bq * M3_);
#pragma unroll
    for (int w = 0; w < 3; ++w) {
      unsigned v;
      do { __builtin_amdgcn_s_sleep(2); v = atomicOr(&hs[w], 0u); }
      while (v == 0u || v == 0xAAAAAAAAu);
      qsh[w] = HS_DEC(v);
    }
  }
  __syncthreads();
  const float qx = qsh[0], qy = qsh[1], qz = qsh[2];
  const float q2 = __fadd_rn(__fadd_rn(__fmul_rn(qx,qx), __fmul_rn(qy,qy)), __fmul_rn(qz,qz));

  // d2 = (q2 + p2) - 2*qp (reference op order) into registers; inline top-2 (lowest-idx ties)
  float d2v[PPC];
  float m1 = FLTMAX, m2 = FLTMAX; int i1 = t*PPC, i2 = t*PPC;
  {
    const float4* gs = (const float4*)gxyz;
#pragma unroll
    for (int g8 = 0; g8 < 2; ++g8) {
      float f[24];
#pragma unroll
      for (int w = 0; w < 6; ++w) {
        const float4 v = gs[t * 12 + g8 * 6 + w];
        f[w*4+0] = v.x; f[w*4+1] = v.y; f[w*4+2] = v.z; f[w*4+3] = v.w;
      }
#pragma unroll
      for (int m = 0; m < 8; ++m) {
        const int j = g8 * 8 + m;
        const float px = f[3*m], py = f[3*m+1], pz = f[3*m+2];
        const float p2 = __fadd_rn(__fadd_rn(__fmul_rn(px,px), __fmul_rn(py,py)), __fmul_rn(pz,pz));
        const float qp = __fadd_rn(__fadd_rn(__fmul_rn(qx,px), __fmul_rn(qy,py)), __fmul_rn(qz,pz));
        const float d  = __fsub_rn(__fadd_rn(q2, p2), __fmul_rn(2.0f, qp));
        d2v[j] = d;
        const int idx = t*PPC + j;
        const bool c1 = d < m1;
        const bool c2 = d < m2;
        const float nm2 = c1 ? m1 : (c2 ? d : m2);
        const int   ni2 = c1 ? i1 : (c2 ? idx : i2);
        m1 = c1 ? d : m1; i1 = c1 ? idx : i1;
        m2 = nm2; i2 = ni2;
      }
    }
  }

  // top-32: 1 barrier/round; DPP min; extraction promotes cached 2nd-min, rescan only if stale
  int myk_idx = 0; float myk_d = 0.0f; int k0_idx = 0;
  unsigned removed = 0u; bool have2 = true;
  for (int kk = 0; kk < K_; ++kk) {
    const int p = kk & 1;
    const unsigned key = f2key(m1);
    const unsigned kmin = dpp_umin_bcast(key);
    const int fl = __ffsll(__ballot(key == kmin)) - 1;
    if (lane == fl) { sval[p][wv_] = m1; sidx[p][wv_] = i1; }
    __syncthreads();
    float wv = sval[p][0]; int wi = sidx[p][0];
#pragma unroll
    for (int u = 1; u < FNW; ++u) {
      const float v = sval[p][u]; const int ii = sidx[p][u];
      if (v < wv || (v == wv && ii < wi)) { wv = v; wi = ii; }
    }
    wi &= (N1_ - 1);
    if ((t >> 4) == kk) { myk_idx = wi; myk_d = wv; }
    if (kk == 0) k0_idx = wi;
    if (kk < K_ - 1 && t == (wi >> 4)) {
      removed |= 1u << (wi & 15);
      if (have2) { m1 = m2; i1 = i2; have2 = false; }
      else {
        m1 = FLTMAX; i1 = t*PPC; m2 = FLTMAX; i2 = t*PPC;
#pragma unroll
        for (int j = 0; j < PPC; ++j) {
          const float d = ((removed >> j) & 1u) ? FLTMAX : d2v[j];
          const int idx = t*PPC + j;
          const bool c1 = d < m1;
          const bool c2 = d < m2;
          const float nm2 = c1 ? m1 : (c2 ? d : m2);
          const int   ni2 = c1 ? i1 : (c2 ? idx : i2);
          m1 = c1 ? d : m1; i1 = c1 ? idx : i1;
          m2 = nm2; i2 = ni2;
        }
        have2 = true;
      }
    }
  }

  // -------- phase 2: gather h0 (same buf0 image as R10), MLP, maxpool --------
  {
    const int k = t >> 4, fg = t & 15;     // 32 k-groups x 16 feature-subgroups
    int nk = myk_idx;
    if (myk_d > 0.04f) nk = k0_idx;        // ball-query radius clamp
    nk &= (N1_ - 1);
    const float4 f0 = *(const float4*)(feat + ((size_t)(b * N1_ + nk)) * F1_ + fg * 4);
    const int fb = 3 + fg * 4;
    buf0[(fb+0)*HSTR + k] = f0.x;
    buf0[(fb+1)*HSTR + k] = f0.y;
    buf0[(fb+2)*HSTR + k] = f0.z;
    buf0[(fb+3)*HSTR + k] = f0.w;
    if (fg < 3) {
      const float pc = gxyz[(size_t)nk * 3 + fg];
      const float qc = (fg == 0) ? qx : (fg == 1) ? qy : qz;
      buf0[fg * HSTR + k] = __fsub_rn(pc, qc);
    }
  }
  __syncthreads();

#define LEAKY_STORE1(acc, biasg, hout) { \
    const float bb = biasg[mg]; \
    float4 v; \
    v.x = acc.x + bb; v.x = fmaxf(v.x, 0.2f*v.x); \
    v.y = acc.y + bb; v.y = fmaxf(v.y, 0.2f*v.y); \
    v.z = acc.z + bb; v.z = fmaxf(v.z, 0.2f*v.z); \
    v.w = acc.w + bb; v.w = fmaxf(v.w, 0.2f*v.w); \
    *(float4*)&hout[mg * HSTR + kq * 4] = v; }

  // layer 1: 67 -> 64 (512 threads: 1m x 4k tiles; ascending-c order => bit-exact per output)
  {
    const int kq = t & 7, mg = t >> 3;   // mg 0..63
    float4 a0 = {0,0,0,0};
#pragma unroll 4
    for (int c = 0; c < CIN_; ++c) {
      const float w = w0g[c * M1_ + mg];
      const float4 h = *(const float4*)&buf0[c * HSTR + kq * 4];
      a0.x += h.x*w; a0.y += h.y*w; a0.z += h.z*w; a0.w += h.w*w;
    }
    LEAKY_STORE1(a0, b0g, buf1)
  }
  __syncthreads();

  // layer 2: 64 -> 64
  {
    const int kq = t & 7, mg = t >> 3;
    float4 a0 = {0,0,0,0};
#pragma unroll 4
    for (int c = 0; c < M1_; ++c) {
      const float w = w1g[c * M2_ + mg];
      const float4 h = *(const float4*)&buf1[c * HSTR + kq * 4];
      a0.x += h.x*w; a0.y += h.y*w; a0.z += h.z*w; a0.w += h.w*w;
    }
    LEAKY_STORE1(a0, b1g, buf0)
  }
#undef LEAKY_STORE1
  __syncthreads();

  // layer 3: 64 -> 128 (2m x 4k per thread), + maxpool over k
  {
    const int kq = t & 7, mg = t >> 3;   // mg 0..63 -> m = 2*mg, 2*mg+1
    float4 a0 = {0,0,0,0}, a1 = {0,0,0,0};
#pragma unroll 4
    for (int c = 0; c < M2_; ++c) {
      const float2 wp = *(const float2*)&w2g[c * M3_ + mg * 2];
      const float4 h  = *(const float4*)&buf0[c * HSTR + kq * 4];
      a0.x += h.x*wp.x; a0.y += h.y*wp.x; a0.z += h.z*wp.x; a0.w += h.w*wp.x;
      a1.x += h.x*wp.y; a1.y += h.y*wp.y; a1.z += h.z*wp.y; a1.w += h.w*wp.y;
    }
    float vm[2];
#define BIAS_LEAKY_HMAX(acc, mi_) { \
      const float bb = b2g[mg*2 + (mi_)]; \
      float vx = acc.x + bb; vx = fmaxf(vx, 0.2f*vx); \
      float vy = acc.y + bb; vy = fmaxf(vy, 0.2f*vy); \
      float vz = acc.z + bb; vz = fmaxf(vz, 0.2f*vz); \
      float vw = acc.w + bb; vw = fmaxf(vw, 0.2f*vw); \
      vm[mi_] = fmaxf(fmaxf(vx, vy), fmaxf(vz, vw)); }
    BIAS_LEAKY_HMAX(a0, 0) BIAS_LEAKY_HMAX(a1, 1)
#undef BIAS_LEAKY_HMAX
#pragma unroll
    for (int m = 1; m <= 4; m <<= 1) {
      vm[0] = fmaxf(vm[0], __shfl_xor(vm[0], m, 64));
      vm[1] = fmaxf(vm[1], __shfl_xor(vm[1], m, 64));
    }
    if (kq == 0) {
      float2 o; o.x = vm[0]; o.y = vm[1];
      *(float2*)&out_feat[(size_t)bq * M3_ + mg * 2] = o;   // overwrites this query's handshake words
    }
  }
}

extern "C" void kernel_launch(void* const* d_in, const int* in_sizes, int n_in,
                              void* d_out, int out_size, void* d_ws, size_t ws_size,
                              hipStream_t stream) {
  const float* xyz  = (const float*)d_in[0];
  const float* feat = (const float*)d_in[1];
  const float* w0   = (const float*)d_in[2];
  const float* b0   = (const float*)d_in[3];
  const float* w1   = (const float*)d_in[4];
  const float* b1   = (const float*)d_in[5];
  const float* w2   = (const float*)d_in[6];
  const float* b2   = (const float*)d_in[7];

  float* out_xyz  = (float*)d_out;                  // (8,1024,3) f32
  float* out_feat = out_xyz + B_ * N2_ * 3;         // (8,1024,128) f32

  fused_kernel<<<B_ + B_ * N2_, TPB, 0, stream>>>(xyz, feat, w0, b0, w1, b1, w2, b2,
                                                  out_xyz, out_feat);
}